// Round 6
// baseline (165.346 us; speedup 1.0000x reference)
//
#include <hip/hip_runtime.h>

// GSHashEncoding R6: fused, software-pipelined (gather t+1 overlaps store t).
// Gather is MSHR/latency-bound (~99us measured via R5 split decomposition);
// store is HBM-bound (~60us). Pipeline turns sum (164us) into max.
//   k1: codes fp32 -> bf16 table in ws (2.62 MB, L2-resident)
//   k2: per block: TPB=4 tiles of 256 rows; double-buffered LDS feats;
//       prefetch next tile's 8 bf16 gathers into regs before store loop.

#define RESO    2097152
#define OUT_DIM 48
#define LVL0    65536
#define NCODES  327680
#define BLK     192                    // 3 waves; 192 % 12 == 0
#define TILE    256
#define NITER   16                     // TILE / (BLK/12)
#define TPB     4                      // tiles per block
#define NBLK    (RESO / (TILE * TPB))  // 2048

typedef int            vi4 __attribute__((ext_vector_type(4)));
typedef float          vf4 __attribute__((ext_vector_type(4)));
typedef unsigned short vu4 __attribute__((ext_vector_type(4)));

static __device__ __forceinline__ unsigned short f2bf_rne(float x) {
    unsigned int u = __float_as_uint(x);
    u += 0x7fffu + ((u >> 16) & 1u);
    return (unsigned short)(u >> 16);
}
static __device__ __forceinline__ float bf2f(unsigned short h) {
    return __uint_as_float(((unsigned int)h) << 16);
}

// ---- k1: codes fp32 -> bf16 table ----
__global__ __launch_bounds__(256) void convert_kernel(
    const float* __restrict__ codes, unsigned short* __restrict__ bf)
{
    const int i = blockIdx.x * 256 + threadIdx.x;      // quad index < NCODES
    const vf4 v = ((const vf4*)codes)[i];
    vu4 o;
    o.x = f2bf_rne(v.x); o.y = f2bf_rne(v.y);
    o.z = f2bf_rne(v.z); o.w = f2bf_rne(v.w);
    ((vu4*)bf)[i] = o;
}

// ---- k2: pipelined fused kernel ----
__global__ __launch_bounds__(BLK) void gshash_pipe_kernel(
    const unsigned short* __restrict__ tab,
    const float* __restrict__ W,
    const vi4*   __restrict__ map0,
    const vi4*   __restrict__ map1,
    float*       __restrict__ out)
{
    __shared__ float feats[2][TILE * 8];   // 16 KB double buffer

    const int t     = threadIdx.x;
    const int col4  = t % 12;
    const int rbase = t / 12;

    vf4 Wv[8];
    #pragma unroll
    for (int k = 0; k < 8; ++k)
        Wv[k] = ((const vf4*)(W + k * OUT_DIM))[col4];

    const unsigned short* __restrict__ t1 = tab + LVL0 * 4;
    const size_t tile0 = (size_t)blockIdx.x * TPB;

    vf4 pa0, pb0, pa1, pb1;                // prefetched feats (regs)

    // gather rows [row0+t] (all threads) and [row0+BLK+t] (t<64) of one tile
    #define GATHER(row0)                                                     \
    {                                                                        \
        const vi4 m0 = __builtin_nontemporal_load(&map0[(row0) + t]);        \
        const vi4 m1 = __builtin_nontemporal_load(&map1[(row0) + t]);        \
        pa0.x = bf2f(tab[m0.x * 4 + 0]);                                     \
        pa0.y = bf2f(tab[m0.y * 4 + 1]);                                     \
        pa0.z = bf2f(tab[m0.z * 4 + 2]);                                     \
        pa0.w = bf2f(tab[m0.w * 4 + 3]);                                     \
        pb0.x = bf2f(t1[m1.x * 4 + 0]);                                      \
        pb0.y = bf2f(t1[m1.y * 4 + 1]);                                      \
        pb0.z = bf2f(t1[m1.z * 4 + 2]);                                      \
        pb0.w = bf2f(t1[m1.w * 4 + 3]);                                      \
        if (t < TILE - BLK) {                                                \
            const vi4 n0 = __builtin_nontemporal_load(&map0[(row0) + BLK + t]); \
            const vi4 n1 = __builtin_nontemporal_load(&map1[(row0) + BLK + t]); \
            pa1.x = bf2f(tab[n0.x * 4 + 0]);                                 \
            pa1.y = bf2f(tab[n0.y * 4 + 1]);                                 \
            pa1.z = bf2f(tab[n0.z * 4 + 2]);                                 \
            pa1.w = bf2f(tab[n0.w * 4 + 3]);                                 \
            pb1.x = bf2f(t1[n1.x * 4 + 0]);                                  \
            pb1.y = bf2f(t1[n1.y * 4 + 1]);                                  \
            pb1.z = bf2f(t1[n1.z * 4 + 2]);                                  \
            pb1.w = bf2f(t1[n1.w * 4 + 3]);                                  \
        }                                                                    \
    }

    #define LDS_WRITE(buf)                                                   \
    {                                                                        \
        *(vf4*)&feats[buf][t * 8]     = pa0;                                 \
        *(vf4*)&feats[buf][t * 8 + 4] = pb0;                                 \
        if (t < TILE - BLK) {                                                \
            *(vf4*)&feats[buf][(BLK + t) * 8]     = pa1;                     \
            *(vf4*)&feats[buf][(BLK + t) * 8 + 4] = pb1;                     \
        }                                                                    \
    }

    // prolog: tile 0
    GATHER(tile0 * TILE);
    LDS_WRITE(0);

    #pragma unroll
    for (int tl = 0; tl < TPB; ++tl) {
        const int cur = tl & 1;

        // issue next tile's gathers BEFORE the store loop (latency hidden)
        if (tl + 1 < TPB) GATHER((tile0 + tl + 1) * TILE);

        __syncthreads();                               // LDS[cur] ready

        vf4* __restrict__ out4 = (vf4*)(out + (tile0 + tl) * TILE * OUT_DIM);
        #pragma unroll
        for (int j = 0; j < NITER; ++j) {
            const int r = j * 16 + rbase;
            const vf4 fa = *(const vf4*)&feats[cur][r * 8];
            const vf4 fb = *(const vf4*)&feats[cur][r * 8 + 4];
            vf4 acc = fa.x * Wv[0];
            acc += fa.y * Wv[1];
            acc += fa.z * Wv[2];
            acc += fa.w * Wv[3];
            acc += fb.x * Wv[4];
            acc += fb.y * Wv[5];
            acc += fb.z * Wv[6];
            acc += fb.w * Wv[7];
            __builtin_nontemporal_store(acc, &out4[j * BLK + t]);
        }

        if (tl + 1 < TPB) LDS_WRITE(cur ^ 1);          // vmcnt wait lands here
    }
    #undef GATHER
    #undef LDS_WRITE
}

// ---- fallback: fused fp32 single-tile kernel (if ws too small) ----
__global__ __launch_bounds__(BLK) void gshash_f32_kernel(
    const float* __restrict__ codes,
    const float* __restrict__ W,
    const vi4*   __restrict__ map0,
    const vi4*   __restrict__ map1,
    float*       __restrict__ out)
{
    __shared__ float feats[TILE * 8];
    const int t     = threadIdx.x;
    const int col4  = t % 12;
    const int rbase = t / 12;
    const size_t row0 = (size_t)blockIdx.x * TILE;

    vf4 Wv[8];
    #pragma unroll
    for (int k = 0; k < 8; ++k)
        Wv[k] = ((const vf4*)(W + k * OUT_DIM))[col4];

    const float* __restrict__ c1 = codes + LVL0 * 4;
    #pragma unroll
    for (int half = 0; half < 2; ++half) {
        const int r = half * BLK + t;
        if (half == 0 || t < TILE - BLK) {
            const vi4 m0 = __builtin_nontemporal_load(&map0[row0 + r]);
            const vi4 m1 = __builtin_nontemporal_load(&map1[row0 + r]);
            vf4 a, b;
            a.x = codes[m0.x * 4 + 0];
            a.y = codes[m0.y * 4 + 1];
            a.z = codes[m0.z * 4 + 2];
            a.w = codes[m0.w * 4 + 3];
            b.x = c1[m1.x * 4 + 0];
            b.y = c1[m1.y * 4 + 1];
            b.z = c1[m1.z * 4 + 2];
            b.w = c1[m1.w * 4 + 3];
            *(vf4*)&feats[r * 8]     = a;
            *(vf4*)&feats[r * 8 + 4] = b;
        }
    }
    __syncthreads();

    vf4* __restrict__ out4 = (vf4*)(out + row0 * OUT_DIM);
    #pragma unroll
    for (int j = 0; j < NITER; ++j) {
        const int r = j * 16 + rbase;
        const vf4 fa = *(const vf4*)&feats[r * 8];
        const vf4 fb = *(const vf4*)&feats[r * 8 + 4];
        vf4 acc = fa.x * Wv[0];
        acc += fa.y * Wv[1];
        acc += fa.z * Wv[2];
        acc += fa.w * Wv[3];
        acc += fb.x * Wv[4];
        acc += fb.y * Wv[5];
        acc += fb.z * Wv[6];
        acc += fb.w * Wv[7];
        __builtin_nontemporal_store(acc, &out4[j * BLK + t]);
    }
}

extern "C" void kernel_launch(void* const* d_in, const int* in_sizes, int n_in,
                              void* d_out, int out_size, void* d_ws, size_t ws_size,
                              hipStream_t stream) {
    const float* codes = (const float*)d_in[0];
    const float* W     = (const float*)d_in[1];
    const vi4*   map0  = (const vi4*)d_in[2];
    const vi4*   map1  = (const vi4*)d_in[3];
    float*       out   = (float*)d_out;

    const size_t tab_bytes = (size_t)NCODES * 4 * sizeof(unsigned short); // 2.62 MB

    if (ws_size >= tab_bytes) {
        unsigned short* tab = (unsigned short*)d_ws;
        convert_kernel<<<NCODES / 256, 256, 0, stream>>>(codes, tab);
        gshash_pipe_kernel<<<NBLK, BLK, 0, stream>>>(tab, W, map0, map1, out);
    } else {
        gshash_f32_kernel<<<RESO / TILE, BLK, 0, stream>>>(codes, W, map0, map1, out);
    }
}

// Round 7
// 148.753 us; speedup vs baseline: 1.1115x; 1.1115x over previous
//
#include <hip/hip_runtime.h>

// GSHashEncoding R7: corrected 2-stage software pipeline.
// R6 failed because hipcc drains vmcnt(0) at every s_barrier, and the barrier
// sat BETWEEN gather-issue and consume. New order per iteration:
//   issue maps(i+2) -> issue gathers(i+1) (maps already in regs)
//   -> consume tile i (16 coalesced nt stores; hides gather latency)
//   -> wait + convert + LDS_WRITE(i+1) -> barrier (drain now harmless).
// k1: codes fp32 -> bf16 table in ws (2.62 MB, L2-resident).

#define RESO    2097152
#define OUT_DIM 48
#define LVL0    65536
#define NCODES  327680
#define BLK     192                    // 3 waves; 192 % 12 == 0
#define TILE    256
#define NITER   16                     // TILE / (BLK/12)
#define TPB     4                      // tiles per block
#define NBLK    (RESO / (TILE * TPB))  // 2048

typedef int            vi4 __attribute__((ext_vector_type(4)));
typedef float          vf4 __attribute__((ext_vector_type(4)));
typedef unsigned short vu4 __attribute__((ext_vector_type(4)));

static __device__ __forceinline__ unsigned short f2bf_rne(float x) {
    unsigned int u = __float_as_uint(x);
    u += 0x7fffu + ((u >> 16) & 1u);
    return (unsigned short)(u >> 16);
}
static __device__ __forceinline__ float bf2f(unsigned short h) {
    return __uint_as_float(((unsigned int)h) << 16);
}

// ---- k1: codes fp32 -> bf16 table ----
__global__ __launch_bounds__(256) void convert_kernel(
    const float* __restrict__ codes, unsigned short* __restrict__ bf)
{
    const int i = blockIdx.x * 256 + threadIdx.x;
    const vf4 v = ((const vf4*)codes)[i];
    vu4 o;
    o.x = f2bf_rne(v.x); o.y = f2bf_rne(v.y);
    o.z = f2bf_rne(v.z); o.w = f2bf_rne(v.w);
    ((vu4*)bf)[i] = o;
}

// ---- k2: pipelined fused kernel ----
__global__ __launch_bounds__(BLK) void gshash_pipe_kernel(
    const unsigned short* __restrict__ tab,
    const float* __restrict__ W,
    const vi4*   __restrict__ map0,
    const vi4*   __restrict__ map1,
    float*       __restrict__ out)
{
    __shared__ float feats[2][TILE * 8];   // 16 KB double buffer

    const int t     = threadIdx.x;
    const int col4  = t % 12;
    const int rbase = t / 12;

    vf4 Wv[8];
    #pragma unroll
    for (int k = 0; k < 8; ++k)
        Wv[k] = ((const vf4*)(W + k * OUT_DIM))[col4];

    const unsigned short* __restrict__ t1 = tab + LVL0 * 4;
    const size_t row00 = (size_t)blockIdx.x * (TPB * TILE);

    vi4 m0b[2], m1b[2], n0b[2], n1b[2];    // double-buffered map regs
    unsigned short g[16];                  // in-flight gathered bf16 (raw)

    // issue map loads for tile j into slot s (no use of data here)
    #define LOADMAPS(j, s) {                                                  \
        const size_t r0 = row00 + (size_t)(j) * TILE;                         \
        m0b[s] = __builtin_nontemporal_load(&map0[r0 + t]);                   \
        m1b[s] = __builtin_nontemporal_load(&map1[r0 + t]);                   \
        if (t < TILE - BLK) {                                                 \
            n0b[s] = __builtin_nontemporal_load(&map0[r0 + BLK + t]);         \
            n1b[s] = __builtin_nontemporal_load(&map1[r0 + BLK + t]);         \
        } }

    // issue gather loads using slot s (addresses from regs; data used later)
    #define GATHERS(s) {                                                      \
        g[0] = tab[m0b[s].x * 4 + 0];                                         \
        g[1] = tab[m0b[s].y * 4 + 1];                                         \
        g[2] = tab[m0b[s].z * 4 + 2];                                         \
        g[3] = tab[m0b[s].w * 4 + 3];                                         \
        g[4] = t1[m1b[s].x * 4 + 0];                                          \
        g[5] = t1[m1b[s].y * 4 + 1];                                          \
        g[6] = t1[m1b[s].z * 4 + 2];                                          \
        g[7] = t1[m1b[s].w * 4 + 3];                                          \
        if (t < TILE - BLK) {                                                 \
            g[8]  = tab[n0b[s].x * 4 + 0];                                    \
            g[9]  = tab[n0b[s].y * 4 + 1];                                    \
            g[10] = tab[n0b[s].z * 4 + 2];                                    \
            g[11] = tab[n0b[s].w * 4 + 3];                                    \
            g[12] = t1[n1b[s].x * 4 + 0];                                     \
            g[13] = t1[n1b[s].y * 4 + 1];                                     \
            g[14] = t1[n1b[s].z * 4 + 2];                                     \
            g[15] = t1[n1b[s].w * 4 + 3];                                     \
        } }

    // convert + write gathered feats into LDS buffer
    #define LDSWRITE(buf) {                                                   \
        vf4 a, b;                                                             \
        a.x = bf2f(g[0]); a.y = bf2f(g[1]); a.z = bf2f(g[2]); a.w = bf2f(g[3]); \
        b.x = bf2f(g[4]); b.y = bf2f(g[5]); b.z = bf2f(g[6]); b.w = bf2f(g[7]); \
        *(vf4*)&feats[buf][t * 8]     = a;                                    \
        *(vf4*)&feats[buf][t * 8 + 4] = b;                                    \
        if (t < TILE - BLK) {                                                 \
            vf4 c, d;                                                         \
            c.x = bf2f(g[8]);  c.y = bf2f(g[9]);  c.z = bf2f(g[10]); c.w = bf2f(g[11]); \
            d.x = bf2f(g[12]); d.y = bf2f(g[13]); d.z = bf2f(g[14]); d.w = bf2f(g[15]); \
            *(vf4*)&feats[buf][(BLK + t) * 8]     = c;                        \
            *(vf4*)&feats[buf][(BLK + t) * 8 + 4] = d;                        \
        } }

    // prolog: tiles 0,1 maps; tile 0 gathers -> LDS[0]
    LOADMAPS(0, 0);
    LOADMAPS(1, 1);
    GATHERS(0);
    LDSWRITE(0);
    __syncthreads();                       // drains slot-1 maps too (harmless)

    #pragma unroll
    for (int i = 0; i < TPB; ++i) {
        const int cur = i & 1;

        if (i + 2 < TPB) LOADMAPS(i + 2, cur);       // slot cur is free now
        if (i + 1 < TPB) GATHERS(cur ^ 1);           // issue; data used after consume

        // consume tile i (gather latency hides under these 16 stores)
        vf4* __restrict__ out4 = (vf4*)(out + (row00 + (size_t)i * TILE) * OUT_DIM);
        #pragma unroll
        for (int j = 0; j < NITER; ++j) {
            const int r = j * 16 + rbase;
            const vf4 fa = *(const vf4*)&feats[cur][r * 8];
            const vf4 fb = *(const vf4*)&feats[cur][r * 8 + 4];
            vf4 acc = fa.x * Wv[0];
            acc += fa.y * Wv[1];
            acc += fa.z * Wv[2];
            acc += fa.w * Wv[3];
            acc += fb.x * Wv[4];
            acc += fb.y * Wv[5];
            acc += fb.z * Wv[6];
            acc += fb.w * Wv[7];
            __builtin_nontemporal_store(acc, &out4[j * BLK + t]);
        }

        if (i + 1 < TPB) {
            LDSWRITE(cur ^ 1);             // counted-vmcnt wait lands HERE
            __syncthreads();
        }
    }
    #undef LOADMAPS
    #undef GATHERS
    #undef LDSWRITE
}

// ---- fallback: fused fp32 single-tile kernel (if ws too small) ----
__global__ __launch_bounds__(BLK) void gshash_f32_kernel(
    const float* __restrict__ codes,
    const float* __restrict__ W,
    const vi4*   __restrict__ map0,
    const vi4*   __restrict__ map1,
    float*       __restrict__ out)
{
    __shared__ float feats[TILE * 8];
    const int t     = threadIdx.x;
    const int col4  = t % 12;
    const int rbase = t / 12;
    const size_t row0 = (size_t)blockIdx.x * TILE;

    vf4 Wv[8];
    #pragma unroll
    for (int k = 0; k < 8; ++k)
        Wv[k] = ((const vf4*)(W + k * OUT_DIM))[col4];

    const float* __restrict__ c1 = codes + LVL0 * 4;
    #pragma unroll
    for (int half = 0; half < 2; ++half) {
        const int r = half * BLK + t;
        if (half == 0 || t < TILE - BLK) {
            const vi4 m0 = __builtin_nontemporal_load(&map0[row0 + r]);
            const vi4 m1 = __builtin_nontemporal_load(&map1[row0 + r]);
            vf4 a, b;
            a.x = codes[m0.x * 4 + 0];
            a.y = codes[m0.y * 4 + 1];
            a.z = codes[m0.z * 4 + 2];
            a.w = codes[m0.w * 4 + 3];
            b.x = c1[m1.x * 4 + 0];
            b.y = c1[m1.y * 4 + 1];
            b.z = c1[m1.z * 4 + 2];
            b.w = c1[m1.w * 4 + 3];
            *(vf4*)&feats[r * 8]     = a;
            *(vf4*)&feats[r * 8 + 4] = b;
        }
    }
    __syncthreads();

    vf4* __restrict__ out4 = (vf4*)(out + row0 * OUT_DIM);
    #pragma unroll
    for (int j = 0; j < NITER; ++j) {
        const int r = j * 16 + rbase;
        const vf4 fa = *(const vf4*)&feats[r * 8];
        const vf4 fb = *(const vf4*)&feats[r * 8 + 4];
        vf4 acc = fa.x * Wv[0];
        acc += fa.y * Wv[1];
        acc += fa.z * Wv[2];
        acc += fa.w * Wv[3];
        acc += fb.x * Wv[4];
        acc += fb.y * Wv[5];
        acc += fb.z * Wv[6];
        acc += fb.w * Wv[7];
        __builtin_nontemporal_store(acc, &out4[j * BLK + t]);
    }
}

extern "C" void kernel_launch(void* const* d_in, const int* in_sizes, int n_in,
                              void* d_out, int out_size, void* d_ws, size_t ws_size,
                              hipStream_t stream) {
    const float* codes = (const float*)d_in[0];
    const float* W     = (const float*)d_in[1];
    const vi4*   map0  = (const vi4*)d_in[2];
    const vi4*   map1  = (const vi4*)d_in[3];
    float*       out   = (float*)d_out;

    const size_t tab_bytes = (size_t)NCODES * 4 * sizeof(unsigned short); // 2.62 MB

    if (ws_size >= tab_bytes) {
        unsigned short* tab = (unsigned short*)d_ws;
        convert_kernel<<<NCODES / 256, 256, 0, stream>>>(codes, tab);
        gshash_pipe_kernel<<<NBLK, BLK, 0, stream>>>(tab, W, map0, map1, out);
    } else {
        gshash_f32_kernel<<<RESO / TILE, BLK, 0, stream>>>(codes, W, map0, map1, out);
    }
}